// Round 1
// baseline (202.498 us; speedup 1.0000x reference)
//
#include <hip/hip_runtime.h>
#include <hip/hip_bf16.h>

#define N_ROWS 8192
#define D_DIM  1024
#define DELTA  0.1f
#define EPSF   1e-8f

#define BM 128
#define BN 128
#define BK 32

typedef __attribute__((ext_vector_type(8))) short bf16x8;
typedef __attribute__((ext_vector_type(4))) float f32x4;

__device__ inline unsigned short f2bf(float f) {
    __hip_bfloat16 h = __float2bfloat16(f);
    return *reinterpret_cast<unsigned short*>(&h);
}

// One block per row: compute xx, yy, xy; write normalized bf16 rows + pos.
__global__ __launch_bounds__(256) void norm_kernel(
    const float* __restrict__ X, const float* __restrict__ Y,
    unsigned short* __restrict__ Xn, unsigned short* __restrict__ Yn,
    float* __restrict__ pos)
{
    const int row = blockIdx.x;
    const int t = threadIdx.x;            // 256 threads, 4 f32 each = 1024
    const float4 xv = reinterpret_cast<const float4*>(X + (size_t)row * D_DIM)[t];
    const float4 yv = reinterpret_cast<const float4*>(Y + (size_t)row * D_DIM)[t];

    float xx = xv.x*xv.x + xv.y*xv.y + xv.z*xv.z + xv.w*xv.w;
    float yy = yv.x*yv.x + yv.y*yv.y + yv.z*yv.z + yv.w*yv.w;
    float xy = xv.x*yv.x + xv.y*yv.y + xv.z*yv.z + xv.w*yv.w;

    #pragma unroll
    for (int off = 32; off > 0; off >>= 1) {
        xx += __shfl_xor(xx, off);
        yy += __shfl_xor(yy, off);
        xy += __shfl_xor(xy, off);
    }
    __shared__ float red[12];
    const int wid = t >> 6, lane = t & 63;
    if (lane == 0) { red[wid] = xx; red[4 + wid] = yy; red[8 + wid] = xy; }
    __syncthreads();
    xx = red[0] + red[1] + red[2] + red[3];
    yy = red[4] + red[5] + red[6] + red[7];
    xy = red[8] + red[9] + red[10] + red[11];

    const float rnx = 1.0f / fmaxf(sqrtf(xx), EPSF);
    const float rny = 1.0f / fmaxf(sqrtf(yy), EPSF);
    if (t == 0) pos[row] = xy * rnx * rny;

    ushort4 ox, oy;
    ox.x = f2bf(xv.x * rnx); ox.y = f2bf(xv.y * rnx);
    ox.z = f2bf(xv.z * rnx); ox.w = f2bf(xv.w * rnx);
    oy.x = f2bf(yv.x * rny); oy.y = f2bf(yv.y * rny);
    oy.z = f2bf(yv.z * rny); oy.w = f2bf(yv.w * rny);
    reinterpret_cast<ushort4*>(Xn + (size_t)row * D_DIM)[t] = ox;
    reinterpret_cast<ushort4*>(Yn + (size_t)row * D_DIM)[t] = oy;
}

#define GLDS16(gptr, lptr) \
    __builtin_amdgcn_global_load_lds((const __attribute__((address_space(1))) void*)(gptr), \
                                     (__attribute__((address_space(3))) void*)(lptr), 16, 0, 0)

// S = Xn * Yn^T tile (128x128), fused hinge + diagonal mask + reduction.
__global__ __launch_bounds__(256) void gemm_loss_kernel(
    const unsigned short* __restrict__ A,   // Xn [N][D] bf16
    const unsigned short* __restrict__ B,   // Yn [N][D] bf16
    const float* __restrict__ pos,
    float* __restrict__ out)
{
    __shared__ __align__(16) unsigned short sA[BM * BK];  // [128][32]
    __shared__ __align__(16) unsigned short sB[BN * BK];  // [128][32]
    __shared__ float sPos[BM];
    __shared__ float redL[4];

    // XCD-aware swizzle over linear 4096-block grid (4096 % 8 == 0 -> bijective)
    const int nwg = gridDim.x;
    const int bid = blockIdx.x;
    const int cpx = nwg >> 3;
    const int swz = (bid & 7) * cpx + (bid >> 3);
    const int row0 = (swz >> 6) * BM;   // 64 tiles per dim
    const int col0 = (swz & 63) * BN;

    const int t = threadIdx.x;
    const int lane = t & 63;
    const int wid = t >> 6;                 // 4 waves, 2x2
    const int waveM = (wid >> 1) * 64;
    const int waveN = (wid & 1) * 64;

    f32x4 acc[4][4] = {};

    const unsigned short* Abase = A + (size_t)row0 * D_DIM;
    const unsigned short* Bbase = B + (size_t)col0 * D_DIM;
    // staging geometry: load q covers 16 tile rows; lane -> row q*16 + (lane>>2), col (lane&3)*8
    const int srow = lane >> 2;
    const int scol = (lane & 3) * 8;

    for (int kk = 0; kk < D_DIM; kk += BK) {
        #pragma unroll
        for (int q2 = 0; q2 < 2; ++q2) {
            const int q = wid * 2 + q2;
            const unsigned short* ga = Abase + (size_t)(q * 16 + srow) * D_DIM + kk + scol;
            const unsigned short* gb = Bbase + (size_t)(q * 16 + srow) * D_DIM + kk + scol;
            GLDS16(ga, sA + q * 512);
            GLDS16(gb, sB + q * 512);
        }
        __syncthreads();

        bf16x8 af[4], bfr[4];
        #pragma unroll
        for (int mi = 0; mi < 4; ++mi) {
            const int r = waveM + mi * 16 + (lane & 15);
            af[mi] = *reinterpret_cast<const bf16x8*>(sA + r * BK + (lane >> 4) * 8);
        }
        #pragma unroll
        for (int ni = 0; ni < 4; ++ni) {
            const int c = waveN + ni * 16 + (lane & 15);
            bfr[ni] = *reinterpret_cast<const bf16x8*>(sB + c * BK + (lane >> 4) * 8);
        }
        #pragma unroll
        for (int mi = 0; mi < 4; ++mi)
            #pragma unroll
            for (int ni = 0; ni < 4; ++ni)
                acc[mi][ni] = __builtin_amdgcn_mfma_f32_16x16x32_bf16(af[mi], bfr[ni], acc[mi][ni], 0, 0, 0);
        __syncthreads();
    }

    // stage pos tile for this block's rows
    if (t < BM) sPos[t] = pos[row0 + t];
    __syncthreads();

    // epilogue: hinge = max(0, DELTA - pos[i] + S[i][j]), skip diagonal, sum
    float local = 0.0f;
    #pragma unroll
    for (int mi = 0; mi < 4; ++mi) {
        #pragma unroll
        for (int j = 0; j < 4; ++j) {
            const int lr = waveM + mi * 16 + (lane >> 4) * 4 + j;  // row within tile
            const int gr = row0 + lr;
            const float base = DELTA - sPos[lr];
            #pragma unroll
            for (int ni = 0; ni < 4; ++ni) {
                const int gc = col0 + waveN + ni * 16 + (lane & 15);
                float h = base + acc[mi][ni][j];
                h = fmaxf(h, 0.0f);
                if (gr == gc) h = 0.0f;
                local += h;
            }
        }
    }
    #pragma unroll
    for (int off = 32; off > 0; off >>= 1) local += __shfl_xor(local, off);
    if (lane == 0) redL[wid] = local;
    __syncthreads();
    if (t == 0) atomicAdd(out, redL[0] + redL[1] + redL[2] + redL[3]);
}

extern "C" void kernel_launch(void* const* d_in, const int* in_sizes, int n_in,
                              void* d_out, int out_size, void* d_ws, size_t ws_size,
                              hipStream_t stream) {
    const float* X = (const float*)d_in[0];
    const float* Y = (const float*)d_in[1];
    float* out = (float*)d_out;

    unsigned short* Xn = (unsigned short*)d_ws;
    unsigned short* Yn = Xn + (size_t)N_ROWS * D_DIM;
    float* pos = (float*)(Yn + (size_t)N_ROWS * D_DIM);

    hipMemsetAsync(d_out, 0, sizeof(float), stream);
    norm_kernel<<<N_ROWS, 256, 0, stream>>>(X, Y, Xn, Yn, pos);
    gemm_loss_kernel<<<dim3((N_ROWS / BM) * (N_ROWS / BN)), 256, 0, stream>>>(Xn, Yn, pos, out);
}